// Round 1
// baseline (1511.780 us; speedup 1.0000x reference)
//
#include <hip/hip_runtime.h>

#define NB 2048

// ---------------------------------------------------------------------------
// Kernel 0: transpose conv2_w [64][32][5][5] -> wT [32*5*5][64]
// ---------------------------------------------------------------------------
__global__ __launch_bounds__(256) void k_transpose_w2(
    const float* __restrict__ w, float* __restrict__ wt)
{
    int i = blockIdx.x * 256 + threadIdx.x;
    if (i >= 64 * 32 * 25) return;
    int co = i / (32 * 25);
    int r  = i % (32 * 25);
    wt[r * 64 + co] = w[i];
}

// ---------------------------------------------------------------------------
// Kernel A: conv1 (1->32, 5x5, pad2) + channel top-4 mask + threshold ReLU
//           + 2x2 maxpool.  One block per image, thread = pooled position.
// out: [B,32,14,14]
// ---------------------------------------------------------------------------
__global__ __launch_bounds__(256) void k_conv1_topk_pool(
    const float* __restrict__ x,     // [B,1,28,28]
    const float* __restrict__ w1,    // [32,1,5,5]
    const float* __restrict__ t,     // [32]
    float* __restrict__ out)         // [B,32,14,14]
{
    __shared__ float xs[32 * 32];    // 28x28 image with 2-halo, zero padded
    const int b   = blockIdx.x;
    const int tid = threadIdx.x;

    for (int i = tid; i < 1024; i += 256) xs[i] = 0.f;
    __syncthreads();
    const float* xb = x + b * 784;
    for (int i = tid; i < 784; i += 256) {
        int y = i / 28, xx = i % 28;
        xs[(y + 2) * 32 + (xx + 2)] = xb[i];
    }
    __syncthreads();

    if (tid >= 196) return;          // no barriers after this point
    const int ph = tid / 14, pw = tid % 14;

    float pmax[32];
#pragma unroll
    for (int c = 0; c < 32; c++) pmax[c] = -3.0e38f;

#pragma unroll
    for (int dy = 0; dy < 2; dy++) {
#pragma unroll
        for (int dx = 0; dx < 2; dx++) {
            float v[32];
#pragma unroll
            for (int c = 0; c < 32; c++) v[c] = 0.f;
            const int row0 = 2 * ph + dy;
            const int col0 = 2 * pw + dx;
#pragma unroll
            for (int ky = 0; ky < 5; ky++) {
#pragma unroll
                for (int kx = 0; kx < 5; kx++) {
                    const float p = xs[(row0 + ky) * 32 + col0 + kx];
#pragma unroll
                    for (int c = 0; c < 32; c++)
                        v[c] = fmaf(p, w1[c * 25 + ky * 5 + kx], v[c]);
                }
            }
            // ---- top-4 (a >= b2 >= c2 >= d2), branchless insertion ----
            float a = -3.0e38f, b2 = -3.0e38f, c2 = -3.0e38f, d2 = -3.0e38f;
#pragma unroll
            for (int c = 0; c < 32; c++) {
                const float vv = v[c];
                const bool ga = vv > a, gb = vv > b2, gc = vv > c2, gd = vv > d2;
                const float nd = gc ? c2 : (gd ? vv : d2);
                const float nc = gb ? b2 : (gc ? vv : c2);
                const float nb = ga ? a  : (gb ? vv : b2);
                const float na = ga ? vv : a;
                a = na; b2 = nb; c2 = nc; d2 = nd;
            }
            // ---- mask (keep >= 4th largest) + running pool max ----
#pragma unroll
            for (int c = 0; c < 32; c++) {
                const float m = (v[c] >= d2) ? v[c] : 0.f;
                pmax[c] = fmaxf(pmax[c], m);
            }
        }
    }

    float* ob = out + b * 32 * 196 + ph * 14 + pw;
#pragma unroll
    for (int c = 0; c < 32; c++)
        ob[c * 196] = fmaxf(pmax[c] - t[c], 0.f);
}

// ---------------------------------------------------------------------------
// Kernel B: conv2 (32->64, 5x5, pad2) + bias + ReLU + 2x2 maxpool.
// One block per image (4 waves), wave = 16-out-channel group,
// lane = pooled position (7x7 = 49 active lanes).
// out: [B,3136] (= [B,64,7,7] flattened)
// ---------------------------------------------------------------------------
__global__ __launch_bounds__(256) void k_conv2_pool(
    const float* __restrict__ in,    // pooled1 [B,32,14,14]
    const float* __restrict__ wt,    // [32*25][64]  (transposed)
    const float* __restrict__ bias,  // [64]
    float* __restrict__ out)         // [B,3136]
{
    __shared__ float xs[32 * 18 * 18];   // 14x14 per ci with 2-halo, zeroed
    const int b   = blockIdx.x;
    const int tid = threadIdx.x;

    for (int i = tid; i < 32 * 18 * 18; i += 256) xs[i] = 0.f;
    __syncthreads();
    const float* ib = in + b * 6272;
    for (int i = tid; i < 6272; i += 256) {
        int ci = i / 196; int r = i % 196; int y = r / 14, xx = r % 14;
        xs[ci * 324 + (y + 2) * 18 + (xx + 2)] = ib[i];
    }
    __syncthreads();

    const int wave = tid >> 6;   // output-channel group (0..3)
    const int lane = tid & 63;
    if (lane >= 49) return;      // no barriers after this point
    const int py = lane / 7, px = lane % 7;

    float acc[4][16] = {};
    const float* wg = wt + wave * 16;
    const int row0 = 2 * py, col0 = 2 * px;

    for (int ci = 0; ci < 32; ci++) {
        const float* xci = xs + ci * 324;
#pragma unroll
        for (int ky = 0; ky < 5; ky++) {
#pragma unroll
            for (int kx = 0; kx < 5; kx++) {
                const float* wrow = wg + (ci * 25 + ky * 5 + kx) * 64;
                const float p00 = xci[(row0 + ky) * 18 + col0 + kx];
                const float p01 = xci[(row0 + ky) * 18 + col0 + kx + 1];
                const float p10 = xci[(row0 + ky + 1) * 18 + col0 + kx];
                const float p11 = xci[(row0 + ky + 1) * 18 + col0 + kx + 1];
#pragma unroll
                for (int co = 0; co < 16; co++) {
                    const float wv = wrow[co];
                    acc[0][co] = fmaf(p00, wv, acc[0][co]);
                    acc[1][co] = fmaf(p01, wv, acc[1][co]);
                    acc[2][co] = fmaf(p10, wv, acc[2][co]);
                    acc[3][co] = fmaf(p11, wv, acc[3][co]);
                }
            }
        }
    }

    const float* bptr = bias + wave * 16;
    float* ob = out + b * 3136 + (wave * 16) * 49 + py * 7 + px;
#pragma unroll
    for (int co = 0; co < 16; co++) {
        const float bv = bptr[co];
        const float m0 = fmaxf(acc[0][co] + bv, 0.f);
        const float m1 = fmaxf(acc[1][co] + bv, 0.f);
        const float m2 = fmaxf(acc[2][co] + bv, 0.f);
        const float m3 = fmaxf(acc[3][co] + bv, 0.f);
        ob[co * 49] = fmaxf(fmaxf(m0, m1), fmaxf(m2, m3));
    }
}

// ---------------------------------------------------------------------------
// Kernel C: fc1  out[2048,1024] = relu(act[2048,3136] @ w[1024,3136]^T + b)
// 64x64 tile per block, 4x4 per thread, K-step 16.
// ---------------------------------------------------------------------------
__global__ __launch_bounds__(256) void k_fc1(
    const float* __restrict__ act,
    const float* __restrict__ w,
    const float* __restrict__ bias,
    float* __restrict__ out)
{
    __shared__ float As[16 * 68];
    __shared__ float Bs[16 * 68];
    const int tid = threadIdx.x;
    const int m0 = blockIdx.y * 64;
    const int n0 = blockIdx.x * 64;
    const int tx = tid & 15, ty = tid >> 4;
    const int lr = tid >> 2;         // row 0..63 within tile (load)
    const int lk = (tid & 3) * 4;    // k offset (load)

    float acc[4][4] = {};
    const float* aptr = act + (size_t)(m0 + lr) * 3136 + lk;
    const float* bptr = w   + (size_t)(n0 + lr) * 3136 + lk;

    for (int k0 = 0; k0 < 3136; k0 += 16) {
        const float4 av = *(const float4*)aptr; aptr += 16;
        const float4 bv = *(const float4*)bptr; bptr += 16;
        __syncthreads();   // previous compute done before overwrite
        As[(lk + 0) * 68 + lr] = av.x;
        As[(lk + 1) * 68 + lr] = av.y;
        As[(lk + 2) * 68 + lr] = av.z;
        As[(lk + 3) * 68 + lr] = av.w;
        Bs[(lk + 0) * 68 + lr] = bv.x;
        Bs[(lk + 1) * 68 + lr] = bv.y;
        Bs[(lk + 2) * 68 + lr] = bv.z;
        Bs[(lk + 3) * 68 + lr] = bv.w;
        __syncthreads();
#pragma unroll
        for (int kk = 0; kk < 16; kk++) {
            const float4 a4 = *(const float4*)&As[kk * 68 + ty * 4];
            const float4 b4 = *(const float4*)&Bs[kk * 68 + tx * 4];
            const float aa[4] = {a4.x, a4.y, a4.z, a4.w};
            const float bb[4] = {b4.x, b4.y, b4.z, b4.w};
#pragma unroll
            for (int i = 0; i < 4; i++)
#pragma unroll
                for (int j = 0; j < 4; j++)
                    acc[i][j] = fmaf(aa[i], bb[j], acc[i][j]);
        }
    }

#pragma unroll
    for (int j = 0; j < 4; j++) {
        const float bv = bias[n0 + tx * 4 + j];
#pragma unroll
        for (int i = 0; i < 4; i++)
            out[(size_t)(m0 + ty * 4 + i) * 1024 + n0 + tx * 4 + j] =
                fmaxf(acc[i][j] + bv, 0.f);
    }
}

// ---------------------------------------------------------------------------
// Kernel D: fc2  out[2048,10] = act[2048,1024] @ w[10,1024]^T + b
// wave per row, K split across 64 lanes, shuffle reduce.
// ---------------------------------------------------------------------------
__global__ __launch_bounds__(256) void k_fc2(
    const float* __restrict__ act,
    const float* __restrict__ w,
    const float* __restrict__ bias,
    float* __restrict__ out)
{
    const int row  = blockIdx.x * 4 + (threadIdx.x >> 6);
    const int lane = threadIdx.x & 63;
    const float* a = act + (size_t)row * 1024;
    float acc[10] = {};
    for (int k = lane; k < 1024; k += 64) {
        const float av = a[k];
#pragma unroll
        for (int j = 0; j < 10; j++)
            acc[j] = fmaf(av, w[j * 1024 + k], acc[j]);
    }
#pragma unroll
    for (int j = 0; j < 10; j++) {
        float s = acc[j];
#pragma unroll
        for (int off = 32; off; off >>= 1) s += __shfl_xor(s, off);
        if (lane == 0) out[(size_t)row * 10 + j] = s + bias[j];
    }
}

// ---------------------------------------------------------------------------
extern "C" void kernel_launch(void* const* d_in, const int* in_sizes, int n_in,
                              void* d_out, int out_size, void* d_ws, size_t ws_size,
                              hipStream_t stream)
{
    const float* x   = (const float*)d_in[0];
    const float* w1  = (const float*)d_in[1];
    const float* tr  = (const float*)d_in[2];
    const float* w2  = (const float*)d_in[3];
    const float* b2  = (const float*)d_in[4];
    const float* fw1 = (const float*)d_in[5];
    const float* fb1 = (const float*)d_in[6];
    const float* fw2 = (const float*)d_in[7];
    const float* fb2 = (const float*)d_in[8];
    float* out = (float*)d_out;

    char* ws = (char*)d_ws;
    float* pooled1 = (float*)ws;                              // 51,380,224 B
    float* flat    = (float*)(ws + 51380224);                 // 25,690,112 B
    float* wt2     = (float*)(ws + 51380224 + 25690112);      //    204,800 B
    float* fc1out  = (float*)ws;                              // aliases pooled1

    k_transpose_w2<<<200, 256, 0, stream>>>(w2, wt2);
    k_conv1_topk_pool<<<NB, 256, 0, stream>>>(x, w1, tr, pooled1);
    k_conv2_pool<<<NB, 256, 0, stream>>>(pooled1, wt2, b2, flat);
    k_fc1<<<dim3(16, 32), 256, 0, stream>>>(flat, fw1, fb1, fc1out);
    k_fc2<<<512, 256, 0, stream>>>(fc1out, fw2, fb2, out);
}

// Round 2
// 1133.723 us; speedup vs baseline: 1.3335x; 1.3335x over previous
//
#include <hip/hip_runtime.h>

typedef __attribute__((ext_vector_type(8))) short bf16x8;
typedef __attribute__((ext_vector_type(4))) float f32x4;
typedef __attribute__((ext_vector_type(4))) unsigned int uint4v;

__device__ __forceinline__ unsigned short f2bf(float f) {
    unsigned u = __builtin_bit_cast(unsigned, f);
    return (unsigned short)((u + 0x7FFFu + ((u >> 16) & 1u)) >> 16);
}

// ---------------------------------------------------------------------------
// prep: conv2_w [64][32][5][5] fp32 -> wt bf16 [25 taps][64 co][32 ci]
// ---------------------------------------------------------------------------
__global__ __launch_bounds__(256) void k_prep_w2(
    const float* __restrict__ w, unsigned short* __restrict__ wt)
{
    int i = blockIdx.x * 256 + threadIdx.x;
    if (i >= 51200) return;
    int ci = i & 31, co = (i >> 5) & 63, tp = i >> 11;
    wt[i] = f2bf(w[(co * 32 + ci) * 25 + tp]);
}

// ---------------------------------------------------------------------------
// prep: fc1_w [1024][3136 = co*49+s] fp32 -> bf16 [1024][3136 = s*64+co]
// ---------------------------------------------------------------------------
__global__ __launch_bounds__(256) void k_prep_fw1(
    const float* __restrict__ w, unsigned short* __restrict__ o)
{
    int n = blockIdx.x;
    const float* src = w + (size_t)n * 3136;
    unsigned short* dst = o + (size_t)n * 3136;
    for (int j = threadIdx.x; j < 3136; j += 256) {
        int co = j & 63, s = j >> 6;
        dst[j] = f2bf(src[co * 49 + s]);
    }
}

// ---------------------------------------------------------------------------
// Kernel A: conv1 + top-4 mask + threshold ReLU + 2x2 pool.
// Output: zero-halo padded NHWC bf16 [B][18][18][32]
// ---------------------------------------------------------------------------
__global__ __launch_bounds__(256) void k_conv1_topk_pool(
    const float* __restrict__ x,
    const float* __restrict__ w1,
    const float* __restrict__ t,
    unsigned short* __restrict__ out)
{
    __shared__ float xs[32 * 32];
    const int b = blockIdx.x;
    const int tid = threadIdx.x;
    unsigned short* ob = out + b * 10368;

    // zero the halo (disjoint from interior writes, no barrier needed)
    for (int p = tid; p < 324; p += 256) {
        int y = p / 18, xx = p % 18;
        if (y < 2 || y >= 16 || xx < 2 || xx >= 16) {
            uint4v z = {0u, 0u, 0u, 0u};
            uint4v* dst = (uint4v*)(ob + p * 32);
            dst[0] = z; dst[1] = z; dst[2] = z; dst[3] = z;
        }
    }

    for (int i = tid; i < 1024; i += 256) xs[i] = 0.f;
    __syncthreads();
    const float* xb = x + b * 784;
    for (int i = tid; i < 784; i += 256) {
        int y = i / 28, xx = i % 28;
        xs[(y + 2) * 32 + (xx + 2)] = xb[i];
    }
    __syncthreads();

    if (tid >= 196) return;
    const int ph = tid / 14, pw = tid % 14;

    float pmax[32];
#pragma unroll
    for (int c = 0; c < 32; c++) pmax[c] = -3.0e38f;

#pragma unroll
    for (int dy = 0; dy < 2; dy++) {
#pragma unroll
        for (int dx = 0; dx < 2; dx++) {
            float v[32];
#pragma unroll
            for (int c = 0; c < 32; c++) v[c] = 0.f;
            const int row0 = 2 * ph + dy;
            const int col0 = 2 * pw + dx;
#pragma unroll
            for (int ky = 0; ky < 5; ky++) {
#pragma unroll
                for (int kx = 0; kx < 5; kx++) {
                    const float p = xs[(row0 + ky) * 32 + col0 + kx];
#pragma unroll
                    for (int c = 0; c < 32; c++)
                        v[c] = fmaf(p, w1[c * 25 + ky * 5 + kx], v[c]);
                }
            }
            float a = -3.0e38f, b2 = -3.0e38f, c2 = -3.0e38f, d2 = -3.0e38f;
#pragma unroll
            for (int c = 0; c < 32; c++) {
                const float vv = v[c];
                const bool ga = vv > a, gb = vv > b2, gc = vv > c2, gd = vv > d2;
                const float nd = gc ? c2 : (gd ? vv : d2);
                const float nc = gb ? b2 : (gc ? vv : c2);
                const float nb = ga ? a  : (gb ? vv : b2);
                const float na = ga ? vv : a;
                a = na; b2 = nb; c2 = nc; d2 = nd;
            }
#pragma unroll
            for (int c = 0; c < 32; c++) {
                const float m = (v[c] >= d2) ? v[c] : 0.f;
                pmax[c] = fmaxf(pmax[c], m);
            }
        }
    }

    unsigned short* op = ob + ((ph + 2) * 18 + (pw + 2)) * 32;
    unsigned pk[16];
#pragma unroll
    for (int i = 0; i < 16; i++) {
        const float v0 = fmaxf(pmax[2 * i] - t[2 * i], 0.f);
        const float v1 = fmaxf(pmax[2 * i + 1] - t[2 * i + 1], 0.f);
        pk[i] = (unsigned)f2bf(v0) | ((unsigned)f2bf(v1) << 16);
    }
#pragma unroll
    for (int j = 0; j < 4; j++)
        ((uint4v*)op)[j] = *(uint4v*)&pk[4 * j];
}

// ---------------------------------------------------------------------------
// Kernel B: conv2 as implicit-GEMM MFMA + bias + ReLU + 2x2 pool.
// Block = 1 image, wave = 16-co group. M=196 (13 row tiles), K=800 (25 taps).
// Output flat [B][49*64] bf16, s-major (py*7+px)*64+co.
// ---------------------------------------------------------------------------
template<int NRT>
__device__ __forceinline__ void conv2_tiles(
    const unsigned short* img, const bf16x8* bfrag,
    int rt0, int laneM, int chunk, float bv, float* xp)
{
    int base[NRT];
#pragma unroll
    for (int i = 0; i < NRT; i++) {
        int m = (rt0 + i) * 16 + laneM;          // A row = lane&15
        m = m > 195 ? 195 : m;
        int y = m / 14, xx = m - y * 14;
        base[i] = (y * 18 + xx) * 32 + chunk * 8;
    }
    f32x4 acc[NRT];
#pragma unroll
    for (int i = 0; i < NRT; i++) acc[i] = (f32x4){0.f, 0.f, 0.f, 0.f};

#pragma unroll
    for (int ky = 0; ky < 5; ky++) {
#pragma unroll
        for (int kx = 0; kx < 5; kx++) {
            const int tp = ky * 5 + kx;
            const int off = (ky * 18 + kx) * 32;
#pragma unroll
            for (int i = 0; i < NRT; i++) {
                bf16x8 af = *(const bf16x8*)(img + base[i] + off);
                acc[i] = __builtin_amdgcn_mfma_f32_16x16x32_bf16(
                    af, bfrag[tp], acc[i], 0, 0, 0);
            }
        }
    }
    // D row = chunk*4+r, col = laneM. relu(x+b), pool pairs over x in-lane.
#pragma unroll
    for (int i = 0; i < NRT; i++) {
        const int m0 = (rt0 + i) * 16 + chunk * 4;
        if (m0 + 1 < 196) {
            const float v0 = fmaxf(acc[i][0] + bv, 0.f);
            const float v1 = fmaxf(acc[i][1] + bv, 0.f);
            const int y = m0 / 14, xx = m0 - y * 14;   // xx even
            xp[(y * 7 + (xx >> 1)) * 16 + laneM] = fmaxf(v0, v1);
        }
        const int m2 = m0 + 2;
        if (m2 + 1 < 196) {
            const float v2 = fmaxf(acc[i][2] + bv, 0.f);
            const float v3 = fmaxf(acc[i][3] + bv, 0.f);
            const int y = m2 / 14, xx = m2 - y * 14;
            xp[(y * 7 + (xx >> 1)) * 16 + laneM] = fmaxf(v2, v3);
        }
    }
}

__global__ __launch_bounds__(256) void k_conv2_mfma(
    const unsigned short* __restrict__ in,    // [B][18][18][32] bf16
    const unsigned short* __restrict__ wt,    // [25][64][32] bf16
    const float* __restrict__ bias,
    unsigned short* __restrict__ flat)        // [B][3136] bf16
{
    __shared__ float xpool[4 * 1576];         // per-wave [14][7][16] + pad 8
    const int b = blockIdx.x;
    const int tid = threadIdx.x;
    const int wave = tid >> 6, lane = tid & 63;
    const int laneM = lane & 15, chunk = lane >> 4;
    const int co0 = wave * 16;

    bf16x8 bfrag[25];
    const unsigned short* wp = wt + (co0 + laneM) * 32 + chunk * 8;
#pragma unroll
    for (int tp = 0; tp < 25; tp++)
        bfrag[tp] = *(const bf16x8*)(wp + tp * 2048);

    const unsigned short* img = in + b * 10368;
    const float bv = bias[co0 + laneM];
    float* xp = xpool + wave * 1576;

    conv2_tiles<4>(img, bfrag, 0,  laneM, chunk, bv, xp);
    conv2_tiles<4>(img, bfrag, 4,  laneM, chunk, bv, xp);
    conv2_tiles<4>(img, bfrag, 8,  laneM, chunk, bv, xp);
    conv2_tiles<1>(img, bfrag, 12, laneM, chunk, bv, xp);

    __syncthreads();
    unsigned short* fb = flat + b * 3136;
    for (int i = tid; i < 3136; i += 256) {
        const int co = i & 63, s = i >> 6;
        const int py = s / 7, px = s - py * 7;
        const float* q = xpool + (co >> 4) * 1576 + (2 * py * 7 + px) * 16 + (co & 15);
        fb[i] = f2bf(fmaxf(q[0], q[112]));     // pool over y: rows 2py, 2py+1
    }
}

// ---------------------------------------------------------------------------
// Kernel C: fc1 MFMA GEMM. out[2048,1024] = relu(A[2048,3136] @ B^T + b), bf16.
// Tile 128x64, 4 waves (2x2 of 64x32), BK=32.
// ---------------------------------------------------------------------------
__global__ __launch_bounds__(256) void k_fc1_mfma(
    const unsigned short* __restrict__ A,     // [2048][3136] bf16
    const unsigned short* __restrict__ Bw,    // [1024][3136] bf16 (permuted)
    const float* __restrict__ bias,
    unsigned short* __restrict__ out)         // [2048][1024] bf16
{
    __shared__ unsigned short As[128 * 40];   // +8 pad: conflict-free b128 reads
    __shared__ unsigned short Bs[64 * 40];
    const int tid = threadIdx.x;
    const int m0 = blockIdx.y * 128;
    const int n0 = blockIdx.x * 64;
    const int wave = tid >> 6, lane = tid & 63;
    const int laneM = lane & 15, chunk = lane >> 4;
    const int wr = (wave >> 1) * 64;
    const int wc = (wave & 1) * 32;

    const int arow = tid >> 1;                // 0..127
    const int aco  = (tid & 1) * 16;          // short offset (2 chunks)
    const int brow = tid >> 2;                // 0..63
    const int bco  = (tid & 3) * 8;

    f32x4 acc[4][2];
#pragma unroll
    for (int i = 0; i < 4; i++)
#pragma unroll
        for (int j = 0; j < 2; j++) acc[i][j] = (f32x4){0.f, 0.f, 0.f, 0.f};

    const unsigned short* aptr = A  + (size_t)(m0 + arow) * 3136 + aco;
    const unsigned short* bptr = Bw + (size_t)(n0 + brow) * 3136 + bco;

    for (int k0 = 0; k0 < 3136; k0 += 32) {
        const bf16x8 a0 = *(const bf16x8*)(aptr);
        const bf16x8 a1 = *(const bf16x8*)(aptr + 8);
        const bf16x8 bb = *(const bf16x8*)(bptr);
        aptr += 32; bptr += 32;
        __syncthreads();
        *(bf16x8*)&As[arow * 40 + aco] = a0;
        *(bf16x8*)&As[arow * 40 + aco + 8] = a1;
        *(bf16x8*)&Bs[brow * 40 + bco] = bb;
        __syncthreads();

        bf16x8 af[4], bf[2];
#pragma unroll
        for (int rt = 0; rt < 4; rt++)
            af[rt] = *(const bf16x8*)&As[(wr + rt * 16 + laneM) * 40 + chunk * 8];
#pragma unroll
        for (int ct = 0; ct < 2; ct++)
            bf[ct] = *(const bf16x8*)&Bs[(wc + ct * 16 + laneM) * 40 + chunk * 8];
#pragma unroll
        for (int rt = 0; rt < 4; rt++)
#pragma unroll
            for (int ct = 0; ct < 2; ct++)
                acc[rt][ct] = __builtin_amdgcn_mfma_f32_16x16x32_bf16(
                    af[rt], bf[ct], acc[rt][ct], 0, 0, 0);
    }

#pragma unroll
    for (int ct = 0; ct < 2; ct++) {
        const int col = n0 + wc + ct * 16 + laneM;
        const float bvv = bias[col];
#pragma unroll
        for (int rt = 0; rt < 4; rt++) {
#pragma unroll
            for (int r = 0; r < 4; r++) {
                const int row = m0 + wr + rt * 16 + chunk * 4 + r;
                out[(size_t)row * 1024 + col] =
                    f2bf(fmaxf(acc[rt][ct][r] + bvv, 0.f));
            }
        }
    }
}

// ---------------------------------------------------------------------------
// Kernel D: fc2. act bf16 [2048][1024] @ w[10][1024]^T + b -> fp32 [2048][10]
// ---------------------------------------------------------------------------
__global__ __launch_bounds__(256) void k_fc2(
    const unsigned short* __restrict__ act,
    const float* __restrict__ w,
    const float* __restrict__ bias,
    float* __restrict__ out)
{
    const int row  = blockIdx.x * 4 + (threadIdx.x >> 6);
    const int lane = threadIdx.x & 63;
    const unsigned short* a = act + (size_t)row * 1024;
    float acc[10] = {};
    for (int k = lane; k < 1024; k += 64) {
        const float av = __builtin_bit_cast(float, (unsigned)a[k] << 16);
#pragma unroll
        for (int j = 0; j < 10; j++)
            acc[j] = fmaf(av, w[j * 1024 + k], acc[j]);
    }
#pragma unroll
    for (int j = 0; j < 10; j++) {
        float s = acc[j];
#pragma unroll
        for (int off = 32; off; off >>= 1) s += __shfl_xor(s, off);
        if (lane == 0) out[(size_t)row * 10 + j] = s + bias[j];
    }
}

// ---------------------------------------------------------------------------
extern "C" void kernel_launch(void* const* d_in, const int* in_sizes, int n_in,
                              void* d_out, int out_size, void* d_ws, size_t ws_size,
                              hipStream_t stream)
{
    const float* x   = (const float*)d_in[0];
    const float* w1  = (const float*)d_in[1];
    const float* tr  = (const float*)d_in[2];
    const float* w2  = (const float*)d_in[3];
    const float* b2  = (const float*)d_in[4];
    const float* fw1 = (const float*)d_in[5];
    const float* fb1 = (const float*)d_in[6];
    const float* fw2 = (const float*)d_in[7];
    const float* fb2 = (const float*)d_in[8];
    float* out = (float*)d_out;

    char* ws = (char*)d_ws;
    unsigned short* padded1 = (unsigned short*)ws;                    // 42,467,328 B
    unsigned short* flat    = (unsigned short*)(ws + 42467328);       // 12,845,056 B
    unsigned short* fc1out  = (unsigned short*)(ws + 55312384);       //  4,194,304 B
    unsigned short* wt2     = (unsigned short*)(ws + 59506688);       //    102,400 B
    unsigned short* fw1p    = (unsigned short*)(ws + 59609088);       //  6,422,528 B

    k_prep_w2<<<200, 256, 0, stream>>>(w2, wt2);
    k_prep_fw1<<<1024, 256, 0, stream>>>(fw1, fw1p);
    k_conv1_topk_pool<<<2048, 256, 0, stream>>>(x, w1, tr, padded1);
    k_conv2_mfma<<<2048, 256, 0, stream>>>(padded1, wt2, b2, flat);
    k_fc1_mfma<<<dim3(16, 16), 256, 0, stream>>>(flat, fw1p, fb1, fc1out);
    k_fc2<<<512, 256, 0, stream>>>(fc1out, fw2, fb2, out);
}

// Round 4
// 403.709 us; speedup vs baseline: 3.7447x; 2.8083x over previous
//
#include <hip/hip_runtime.h>

typedef __attribute__((ext_vector_type(8))) short bf16x8;
typedef __attribute__((ext_vector_type(4))) float f32x4;
typedef __attribute__((ext_vector_type(4))) unsigned int uint4v;

__device__ __forceinline__ unsigned short f2bf(float f) {
    unsigned u = __builtin_bit_cast(unsigned, f);
    return (unsigned short)((u + 0x7FFFu + ((u >> 16) & 1u)) >> 16);
}

// ---------------------------------------------------------------------------
// prep: conv2_w [64][32][5][5] fp32 -> wt bf16 [25 taps][64 co][32 ci]
// ---------------------------------------------------------------------------
__global__ __launch_bounds__(256) void k_prep_w2(
    const float* __restrict__ w, unsigned short* __restrict__ wt)
{
    int i = blockIdx.x * 256 + threadIdx.x;
    if (i >= 51200) return;
    int ci = i & 31, co = (i >> 5) & 63, tp = i >> 11;
    wt[i] = f2bf(w[(co * 32 + ci) * 25 + tp]);
}

// ---------------------------------------------------------------------------
// prep: fc1_w [1024][3136 = co*49+s] fp32 -> bf16 [1024][3136 = s*64+co]
// ---------------------------------------------------------------------------
__global__ __launch_bounds__(256) void k_prep_fw1(
    const float* __restrict__ w, unsigned short* __restrict__ o)
{
    int n = blockIdx.x;
    const float* src = w + (size_t)n * 3136;
    unsigned short* dst = o + (size_t)n * 3136;
    for (int j = threadIdx.x; j < 3136; j += 256) {
        int co = j & 63, s = j >> 6;
        dst[j] = f2bf(src[co * 49 + s]);
    }
}

// ---------------------------------------------------------------------------
// Kernel A: conv1 + top-4 mask + threshold ReLU + 2x2 pool.
// w1 staged in LDS as [tap][c] (float4 broadcast reads); min/max top-4 net.
// Output: zero-halo padded NHWC bf16 [B][18][18][32]
// ---------------------------------------------------------------------------
__global__ __launch_bounds__(256) void k_conv1_topk_pool(
    const float* __restrict__ x,
    const float* __restrict__ w1,
    const float* __restrict__ t,
    unsigned short* __restrict__ out)
{
    __shared__ float xs[32 * 32];
    __shared__ float ws[25 * 32];    // [tap][c]
    const int b = blockIdx.x;
    const int tid = threadIdx.x;
    unsigned short* ob = out + b * 10368;

    // zero the halo (disjoint from interior writes, no barrier needed)
    for (int p = tid; p < 324; p += 256) {
        int y = p / 18, xx = p % 18;
        if (y < 2 || y >= 16 || xx < 2 || xx >= 16) {
            uint4v z = {0u, 0u, 0u, 0u};
            uint4v* dst = (uint4v*)(ob + p * 32);
            dst[0] = z; dst[1] = z; dst[2] = z; dst[3] = z;
        }
    }

    for (int i = tid; i < 1024; i += 256) xs[i] = 0.f;
    // stage w1 transposed: ws[tap*32+c] = w1[c*25+tap]
    for (int j = tid; j < 800; j += 256)
        ws[j] = w1[(j & 31) * 25 + (j >> 5)];
    __syncthreads();
    const float* xb = x + b * 784;
    for (int i = tid; i < 784; i += 256) {
        int y = i / 28, xx = i % 28;
        xs[(y + 2) * 32 + (xx + 2)] = xb[i];
    }
    __syncthreads();

    if (tid >= 196) return;          // all barriers are above this point
    const int ph = tid / 14, pw = tid % 14;

    float pmax[32];
#pragma unroll
    for (int c = 0; c < 32; c++) pmax[c] = -3.0e38f;

#pragma unroll
    for (int dy = 0; dy < 2; dy++) {
#pragma unroll
        for (int dx = 0; dx < 2; dx++) {
            float v[32];
#pragma unroll
            for (int c = 0; c < 32; c++) v[c] = 0.f;
            const int row0 = 2 * ph + dy;
            const int col0 = 2 * pw + dx;
#pragma unroll
            for (int ky = 0; ky < 5; ky++) {
#pragma unroll
                for (int kx = 0; kx < 5; kx++) {
                    const float p = xs[(row0 + ky) * 32 + col0 + kx];
                    const float* wrow = ws + (ky * 5 + kx) * 32;
#pragma unroll
                    for (int cg = 0; cg < 8; cg++) {
                        const f32x4 w4 = *(const f32x4*)(wrow + cg * 4);
                        v[cg * 4 + 0] = fmaf(p, w4[0], v[cg * 4 + 0]);
                        v[cg * 4 + 1] = fmaf(p, w4[1], v[cg * 4 + 1]);
                        v[cg * 4 + 2] = fmaf(p, w4[2], v[cg * 4 + 2]);
                        v[cg * 4 + 3] = fmaf(p, w4[3], v[cg * 4 + 3]);
                    }
                }
            }
            // ---- top-4 via min/max insertion network (no cmp/select) ----
            float a = -3.0e38f, b2 = -3.0e38f, c2 = -3.0e38f, d2 = -3.0e38f;
#pragma unroll
            for (int c = 0; c < 32; c++) {
                const float vv = v[c];
                const float m1 = fminf(a, vv);  a  = fmaxf(a, vv);
                const float m2 = fminf(b2, m1); b2 = fmaxf(b2, m1);
                const float m3 = fminf(c2, m2); c2 = fmaxf(c2, m2);
                d2 = fmaxf(d2, m3);
            }
            // ---- mask (keep >= 4th largest) + running pool max ----
#pragma unroll
            for (int c = 0; c < 32; c++) {
                const float m = (v[c] >= d2) ? v[c] : 0.f;
                pmax[c] = fmaxf(pmax[c], m);
            }
        }
    }

    unsigned short* op = ob + ((ph + 2) * 18 + (pw + 2)) * 32;
    unsigned pk[16];
#pragma unroll
    for (int i = 0; i < 16; i++) {
        const float v0 = fmaxf(pmax[2 * i] - t[2 * i], 0.f);
        const float v1 = fmaxf(pmax[2 * i + 1] - t[2 * i + 1], 0.f);
        pk[i] = (unsigned)f2bf(v0) | ((unsigned)f2bf(v1) << 16);
    }
#pragma unroll
    for (int j = 0; j < 4; j++)
        ((uint4v*)op)[j] = *(uint4v*)&pk[4 * j];
}

// ---------------------------------------------------------------------------
// Kernel B: conv2 as implicit-GEMM MFMA + bias + ReLU + 2x2 pool.
// Block = 1 image, wave = 16-co group. M=196 (13 row tiles), K=800 (25 taps).
// Output flat [B][49*64] bf16, s-major (py*7+px)*64+co.
// ---------------------------------------------------------------------------
template<int NRT>
__device__ __forceinline__ void conv2_tiles(
    const unsigned short* img, const bf16x8* bfrag,
    int rt0, int laneM, int chunk, float bv, float* xp)
{
    int base[NRT];
#pragma unroll
    for (int i = 0; i < NRT; i++) {
        int m = (rt0 + i) * 16 + laneM;          // A row = lane&15
        m = m > 195 ? 195 : m;
        int y = m / 14, xx = m - y * 14;
        base[i] = (y * 18 + xx) * 32 + chunk * 8;
    }
    f32x4 acc[NRT];
#pragma unroll
    for (int i = 0; i < NRT; i++) acc[i] = (f32x4){0.f, 0.f, 0.f, 0.f};

#pragma unroll
    for (int ky = 0; ky < 5; ky++) {
#pragma unroll
        for (int kx = 0; kx < 5; kx++) {
            const int tp = ky * 5 + kx;
            const int off = (ky * 18 + kx) * 32;
#pragma unroll
            for (int i = 0; i < NRT; i++) {
                bf16x8 af = *(const bf16x8*)(img + base[i] + off);
                acc[i] = __builtin_amdgcn_mfma_f32_16x16x32_bf16(
                    af, bfrag[tp], acc[i], 0, 0, 0);
            }
        }
    }
    // D row = chunk*4+r, col = laneM. relu(x+b), pool pairs over x in-lane.
#pragma unroll
    for (int i = 0; i < NRT; i++) {
        const int m0 = (rt0 + i) * 16 + chunk * 4;
        if (m0 + 1 < 196) {
            const float v0 = fmaxf(acc[i][0] + bv, 0.f);
            const float v1 = fmaxf(acc[i][1] + bv, 0.f);
            const int y = m0 / 14, xx = m0 - y * 14;   // xx even
            xp[(y * 7 + (xx >> 1)) * 16 + laneM] = fmaxf(v0, v1);
        }
        const int m2 = m0 + 2;
        if (m2 + 1 < 196) {
            const float v2 = fmaxf(acc[i][2] + bv, 0.f);
            const float v3 = fmaxf(acc[i][3] + bv, 0.f);
            const int y = m2 / 14, xx = m2 - y * 14;
            xp[(y * 7 + (xx >> 1)) * 16 + laneM] = fmaxf(v2, v3);
        }
    }
}

__global__ __launch_bounds__(256) void k_conv2_mfma(
    const unsigned short* __restrict__ in,    // [B][18][18][32] bf16
    const unsigned short* __restrict__ wt,    // [25][64][32] bf16
    const float* __restrict__ bias,
    unsigned short* __restrict__ flat)        // [B][3136] bf16
{
    __shared__ float xpool[4 * 1576];         // per-wave [14][7][16] + pad 8
    const int b = blockIdx.x;
    const int tid = threadIdx.x;
    const int wave = tid >> 6, lane = tid & 63;
    const int laneM = lane & 15, chunk = lane >> 4;
    const int co0 = wave * 16;

    bf16x8 bfrag[25];
    const unsigned short* wp = wt + (co0 + laneM) * 32 + chunk * 8;
#pragma unroll
    for (int tp = 0; tp < 25; tp++)
        bfrag[tp] = *(const bf16x8*)(wp + tp * 2048);

    const unsigned short* img = in + b * 10368;
    const float bv = bias[co0 + laneM];
    float* xp = xpool + wave * 1576;

    conv2_tiles<4>(img, bfrag, 0,  laneM, chunk, bv, xp);
    conv2_tiles<4>(img, bfrag, 4,  laneM, chunk, bv, xp);
    conv2_tiles<4>(img, bfrag, 8,  laneM, chunk, bv, xp);
    conv2_tiles<1>(img, bfrag, 12, laneM, chunk, bv, xp);

    __syncthreads();
    unsigned short* fb = flat + b * 3136;
    for (int i = tid; i < 3136; i += 256) {
        const int co = i & 63, s = i >> 6;
        const int py = s / 7, px = s - py * 7;
        const float* q = xpool + (co >> 4) * 1576 + (2 * py * 7 + px) * 16 + (co & 15);
        fb[i] = f2bf(fmaxf(q[0], q[112]));     // pool over y: rows 2py, 2py+1
    }
}

// ---------------------------------------------------------------------------
// Kernel C: fc1 MFMA GEMM. out[2048,1024] = relu(A[2048,3136] @ B^T + b), bf16.
// Tile 128x64, 4 waves (2x2 of 64x32), BK=32.
// ---------------------------------------------------------------------------
__global__ __launch_bounds__(256) void k_fc1_mfma(
    const unsigned short* __restrict__ A,     // [2048][3136] bf16
    const unsigned short* __restrict__ Bw,    // [1024][3136] bf16 (permuted)
    const float* __restrict__ bias,
    unsigned short* __restrict__ out)         // [2048][1024] bf16
{
    __shared__ unsigned short As[128 * 40];   // +8 pad: conflict-free b128 reads
    __shared__ unsigned short Bs[64 * 40];
    const int tid = threadIdx.x;
    const int m0 = blockIdx.y * 128;
    const int n0 = blockIdx.x * 64;
    const int wave = tid >> 6, lane = tid & 63;
    const int laneM = lane & 15, chunk = lane >> 4;
    const int wr = (wave >> 1) * 64;
    const int wc = (wave & 1) * 32;

    const int arow = tid >> 1;                // 0..127
    const int aco  = (tid & 1) * 16;          // short offset (2 chunks)
    const int brow = tid >> 2;                // 0..63
    const int bco  = (tid & 3) * 8;

    f32x4 acc[4][2];
#pragma unroll
    for (int i = 0; i < 4; i++)
#pragma unroll
        for (int j = 0; j < 2; j++) acc[i][j] = (f32x4){0.f, 0.f, 0.f, 0.f};

    const unsigned short* aptr = A  + (size_t)(m0 + arow) * 3136 + aco;
    const unsigned short* bptr = Bw + (size_t)(n0 + brow) * 3136 + bco;

    for (int k0 = 0; k0 < 3136; k0 += 32) {
        const bf16x8 a0 = *(const bf16x8*)(aptr);
        const bf16x8 a1 = *(const bf16x8*)(aptr + 8);
        const bf16x8 bb = *(const bf16x8*)(bptr);
        aptr += 32; bptr += 32;
        __syncthreads();
        *(bf16x8*)&As[arow * 40 + aco] = a0;
        *(bf16x8*)&As[arow * 40 + aco + 8] = a1;
        *(bf16x8*)&Bs[brow * 40 + bco] = bb;
        __syncthreads();

        bf16x8 af[4], bf[2];
#pragma unroll
        for (int rt = 0; rt < 4; rt++)
            af[rt] = *(const bf16x8*)&As[(wr + rt * 16 + laneM) * 40 + chunk * 8];
#pragma unroll
        for (int ct = 0; ct < 2; ct++)
            bf[ct] = *(const bf16x8*)&Bs[(wc + ct * 16 + laneM) * 40 + chunk * 8];
#pragma unroll
        for (int rt = 0; rt < 4; rt++)
#pragma unroll
            for (int ct = 0; ct < 2; ct++)
                acc[rt][ct] = __builtin_amdgcn_mfma_f32_16x16x32_bf16(
                    af[rt], bf[ct], acc[rt][ct], 0, 0, 0);
    }

#pragma unroll
    for (int ct = 0; ct < 2; ct++) {
        const int col = n0 + wc + ct * 16 + laneM;
        const float bvv = bias[col];
#pragma unroll
        for (int rt = 0; rt < 4; rt++) {
#pragma unroll
            for (int r = 0; r < 4; r++) {
                const int row = m0 + wr + rt * 16 + chunk * 4 + r;
                out[(size_t)row * 1024 + col] =
                    f2bf(fmaxf(acc[rt][ct][r] + bvv, 0.f));
            }
        }
    }
}

// ---------------------------------------------------------------------------
// Kernel D: fc2. act bf16 [2048][1024] @ w[10][1024]^T + b -> fp32 [2048][10]
// ---------------------------------------------------------------------------
__global__ __launch_bounds__(256) void k_fc2(
    const unsigned short* __restrict__ act,
    const float* __restrict__ w,
    const float* __restrict__ bias,
    float* __restrict__ out)
{
    const int row  = blockIdx.x * 4 + (threadIdx.x >> 6);
    const int lane = threadIdx.x & 63;
    const unsigned short* a = act + (size_t)row * 1024;
    float acc[10] = {};
    for (int k = lane; k < 1024; k += 64) {
        const float av = __builtin_bit_cast(float, (unsigned)a[k] << 16);
#pragma unroll
        for (int j = 0; j < 10; j++)
            acc[j] = fmaf(av, w[j * 1024 + k], acc[j]);
    }
#pragma unroll
    for (int j = 0; j < 10; j++) {
        float s = acc[j];
#pragma unroll
        for (int off = 32; off; off >>= 1) s += __shfl_xor(s, off);
        if (lane == 0) out[(size_t)row * 10 + j] = s + bias[j];
    }
}

// ---------------------------------------------------------------------------
extern "C" void kernel_launch(void* const* d_in, const int* in_sizes, int n_in,
                              void* d_out, int out_size, void* d_ws, size_t ws_size,
                              hipStream_t stream)
{
    const float* x   = (const float*)d_in[0];
    const float* w1  = (const float*)d_in[1];
    const float* tr  = (const float*)d_in[2];
    const float* w2  = (const float*)d_in[3];
    const float* b2  = (const float*)d_in[4];
    const float* fw1 = (const float*)d_in[5];
    const float* fb1 = (const float*)d_in[6];
    const float* fw2 = (const float*)d_in[7];
    const float* fb2 = (const float*)d_in[8];
    float* out = (float*)d_out;

    char* ws = (char*)d_ws;
    unsigned short* padded1 = (unsigned short*)ws;                    // 42,467,328 B
    unsigned short* flat    = (unsigned short*)(ws + 42467328);       // 12,845,056 B
    unsigned short* fc1out  = (unsigned short*)(ws + 55312384);       //  4,194,304 B
    unsigned short* wt2     = (unsigned short*)(ws + 59506688);       //    102,400 B
    unsigned short* fw1p    = (unsigned short*)(ws + 59609088);       //  6,422,528 B

    k_prep_w2<<<200, 256, 0, stream>>>(w2, wt2);
    k_prep_fw1<<<1024, 256, 0, stream>>>(fw1, fw1p);
    k_conv1_topk_pool<<<2048, 256, 0, stream>>>(x, w1, tr, padded1);
    k_conv2_mfma<<<2048, 256, 0, stream>>>(padded1, wt2, b2, flat);
    k_fc1_mfma<<<dim3(16, 16), 256, 0, stream>>>(flat, fw1p, fb1, fc1out);
    k_fc2<<<512, 256, 0, stream>>>(fc1out, fw2, fb2, out);
}

// Round 5
// 322.277 us; speedup vs baseline: 4.6909x; 1.2527x over previous
//
#include <hip/hip_runtime.h>

typedef __attribute__((ext_vector_type(8))) short bf16x8;
typedef __attribute__((ext_vector_type(4))) float f32x4;
typedef __attribute__((ext_vector_type(16))) float f32x16;
typedef __attribute__((ext_vector_type(4))) unsigned int uint4v;

__device__ __forceinline__ unsigned short f2bf(float f) {
    unsigned u = __builtin_bit_cast(unsigned, f);
    return (unsigned short)((u + 0x7FFFu + ((u >> 16) & 1u)) >> 16);
}

// ---------------------------------------------------------------------------
// prep: conv2_w [64][32][5][5] fp32 -> wt bf16 [25 taps][64 co][32 ci]
// ---------------------------------------------------------------------------
__global__ __launch_bounds__(256) void k_prep_w2(
    const float* __restrict__ w, unsigned short* __restrict__ wt)
{
    int i = blockIdx.x * 256 + threadIdx.x;
    if (i >= 51200) return;
    int ci = i & 31, co = (i >> 5) & 63, tp = i >> 11;
    wt[i] = f2bf(w[(co * 32 + ci) * 25 + tp]);
}

// ---------------------------------------------------------------------------
// prep: fc1_w [1024][3136 = co*49+s] fp32 -> bf16 [1024][3136 = s*64+co]
// ---------------------------------------------------------------------------
__global__ __launch_bounds__(256) void k_prep_fw1(
    const float* __restrict__ w, unsigned short* __restrict__ o)
{
    int n = blockIdx.x;
    const float* src = w + (size_t)n * 3136;
    unsigned short* dst = o + (size_t)n * 3136;
    for (int j = threadIdx.x; j < 3136; j += 256) {
        int co = j & 63, s = j >> 6;
        dst[j] = f2bf(src[co * 49 + s]);
    }
}

// ---------------------------------------------------------------------------
// Kernel A: conv1 + top-4 mask + threshold ReLU + 2x2 pool.
// w1 staged in LDS as [tap][c] (float4 broadcast reads); min/max top-4 net.
// Output: zero-halo padded NHWC bf16 [B][18][18][32]
// ---------------------------------------------------------------------------
__global__ __launch_bounds__(256) void k_conv1_topk_pool(
    const float* __restrict__ x,
    const float* __restrict__ w1,
    const float* __restrict__ t,
    unsigned short* __restrict__ out)
{
    __shared__ float xs[32 * 32];
    __shared__ float ws[25 * 32];    // [tap][c]
    const int b = blockIdx.x;
    const int tid = threadIdx.x;
    unsigned short* ob = out + b * 10368;

    // zero the halo (disjoint from interior writes, no barrier needed)
    for (int p = tid; p < 324; p += 256) {
        int y = p / 18, xx = p % 18;
        if (y < 2 || y >= 16 || xx < 2 || xx >= 16) {
            uint4v z = {0u, 0u, 0u, 0u};
            uint4v* dst = (uint4v*)(ob + p * 32);
            dst[0] = z; dst[1] = z; dst[2] = z; dst[3] = z;
        }
    }

    for (int i = tid; i < 1024; i += 256) xs[i] = 0.f;
    // stage w1 transposed: ws[tap*32+c] = w1[c*25+tap]
    for (int j = tid; j < 800; j += 256)
        ws[j] = w1[(j & 31) * 25 + (j >> 5)];
    __syncthreads();
    const float* xb = x + b * 784;
    for (int i = tid; i < 784; i += 256) {
        int y = i / 28, xx = i % 28;
        xs[(y + 2) * 32 + (xx + 2)] = xb[i];
    }
    __syncthreads();

    if (tid >= 196) return;          // all barriers are above this point
    const int ph = tid / 14, pw = tid % 14;

    float pmax[32];
#pragma unroll
    for (int c = 0; c < 32; c++) pmax[c] = -3.0e38f;

#pragma unroll
    for (int dy = 0; dy < 2; dy++) {
#pragma unroll
        for (int dx = 0; dx < 2; dx++) {
            float v[32];
#pragma unroll
            for (int c = 0; c < 32; c++) v[c] = 0.f;
            const int row0 = 2 * ph + dy;
            const int col0 = 2 * pw + dx;
#pragma unroll
            for (int ky = 0; ky < 5; ky++) {
#pragma unroll
                for (int kx = 0; kx < 5; kx++) {
                    const float p = xs[(row0 + ky) * 32 + col0 + kx];
                    const float* wrow = ws + (ky * 5 + kx) * 32;
#pragma unroll
                    for (int cg = 0; cg < 8; cg++) {
                        const f32x4 w4 = *(const f32x4*)(wrow + cg * 4);
                        v[cg * 4 + 0] = fmaf(p, w4[0], v[cg * 4 + 0]);
                        v[cg * 4 + 1] = fmaf(p, w4[1], v[cg * 4 + 1]);
                        v[cg * 4 + 2] = fmaf(p, w4[2], v[cg * 4 + 2]);
                        v[cg * 4 + 3] = fmaf(p, w4[3], v[cg * 4 + 3]);
                    }
                }
            }
            // ---- top-4 via min/max insertion network (no cmp/select) ----
            float a = -3.0e38f, b2 = -3.0e38f, c2 = -3.0e38f, d2 = -3.0e38f;
#pragma unroll
            for (int c = 0; c < 32; c++) {
                const float vv = v[c];
                const float m1 = fminf(a, vv);  a  = fmaxf(a, vv);
                const float m2 = fminf(b2, m1); b2 = fmaxf(b2, m1);
                const float m3 = fminf(c2, m2); c2 = fmaxf(c2, m2);
                d2 = fmaxf(d2, m3);
            }
            // ---- mask (keep >= 4th largest) + running pool max ----
#pragma unroll
            for (int c = 0; c < 32; c++) {
                const float m = (v[c] >= d2) ? v[c] : 0.f;
                pmax[c] = fmaxf(pmax[c], m);
            }
        }
    }

    unsigned short* op = ob + ((ph + 2) * 18 + (pw + 2)) * 32;
    unsigned pk[16];
#pragma unroll
    for (int i = 0; i < 16; i++) {
        const float v0 = fmaxf(pmax[2 * i] - t[2 * i], 0.f);
        const float v1 = fmaxf(pmax[2 * i + 1] - t[2 * i + 1], 0.f);
        pk[i] = (unsigned)f2bf(v0) | ((unsigned)f2bf(v1) << 16);
    }
#pragma unroll
    for (int j = 0; j < 4; j++)
        ((uint4v*)op)[j] = *(uint4v*)&pk[4 * j];
}

// ---------------------------------------------------------------------------
// Kernel B: conv2 implicit-GEMM, mfma_f32_32x32x16_bf16.
// Block = 2 images, 4 waves: wave = (img = w&1, tile-parity = w>>1).
// Each wave: tiles {par, par+2, par+4, par+6}, BOTH 32-co groups per A-read.
// A from padded LDS ([324][40] shorts, conflict-free b128); B regs per tap.
// Epilogue: x-pool in-lane, y-pool via LDS overlay. flat [B][49*64] bf16.
// ---------------------------------------------------------------------------
__global__ __launch_bounds__(256) void k_conv2_mfma(
    const unsigned short* __restrict__ in,    // [B][324][32] bf16 padded NHWC
    const unsigned short* __restrict__ wt,    // [25][64][32] bf16
    const float* __restrict__ bias,
    unsigned short* __restrict__ flat)        // [B][3136] bf16
{
    __shared__ __align__(16) unsigned short smem[2 * 324 * 40];  // 51840 B
    const int bp   = blockIdx.x;              // image pair
    const int tid  = threadIdx.x;
    const int wave = tid >> 6, lane = tid & 63;
    const int img  = wave & 1;
    const int par  = wave >> 1;               // tile parity
    const int col  = lane & 31;               // A row / B col
    const int hi   = lane >> 5;               // k-half

    // ---- stage 2 images into padded LDS [img][324][40 shorts] ----
    for (int i = tid; i < 2592; i += 256) {
        const int im = i >= 1296;
        const int r  = i - im * 1296;
        const int p  = r >> 2, c = r & 3;
        const bf16x8 v = *(const bf16x8*)(
            in + (size_t)(2 * bp + im) * 10368 + p * 32 + c * 8);
        *(bf16x8*)(smem + im * 12960 + p * 40 + c * 8) = v;
    }
    __syncthreads();

    // per-lane A base per tile (short offsets into smem)
    int pbase[4];
#pragma unroll
    for (int ts = 0; ts < 4; ts++) {
        int m = (par + 2 * ts) * 32 + col;
        m = m > 195 ? 195 : m;
        const int y = m / 14, x = m - y * 14;
        pbase[ts] = img * 12960 + (y * 18 + x) * 40 + hi * 8;
    }
    const unsigned short* wlane = wt + col * 32 + hi * 8;

    f32x16 acc[4][2];
#pragma unroll
    for (int ts = 0; ts < 4; ts++)
#pragma unroll
        for (int g = 0; g < 2; g++)
#pragma unroll
            for (int e = 0; e < 16; e++) acc[ts][g][e] = 0.f;

#pragma unroll
    for (int ky = 0; ky < 5; ky++) {
#pragma unroll
        for (int kx = 0; kx < 5; kx++) {
            const unsigned short* wp = wlane + (ky * 5 + kx) * 2048;
            const bf16x8 b00 = *(const bf16x8*)(wp);           // ks0 g0
            const bf16x8 b01 = *(const bf16x8*)(wp + 1024);    // ks0 g1
            const bf16x8 b10 = *(const bf16x8*)(wp + 16);      // ks1 g0
            const bf16x8 b11 = *(const bf16x8*)(wp + 1040);    // ks1 g1
            const int toff = (ky * 18 + kx) * 40;
#pragma unroll
            for (int ts = 0; ts < 4; ts++) {
                if (par + 2 * ts < 7) {
                    const bf16x8 a0 = *(const bf16x8*)(smem + pbase[ts] + toff);
                    acc[ts][0] = __builtin_amdgcn_mfma_f32_32x32x16_bf16(
                        a0, b00, acc[ts][0], 0, 0, 0);
                    acc[ts][1] = __builtin_amdgcn_mfma_f32_32x32x16_bf16(
                        a0, b01, acc[ts][1], 0, 0, 0);
                    const bf16x8 a1 = *(const bf16x8*)(smem + pbase[ts] + toff + 16);
                    acc[ts][0] = __builtin_amdgcn_mfma_f32_32x32x16_bf16(
                        a1, b10, acc[ts][0], 0, 0, 0);
                    acc[ts][1] = __builtin_amdgcn_mfma_f32_32x32x16_bf16(
                        a1, b11, acc[ts][1], 0, 0, 0);
                }
            }
        }
    }

    // ---- epilogue: relu(acc+bias), x-pool in-lane, y-pool via LDS ----
    __syncthreads();                          // all A-reads done; reuse smem
    float* pool = (float*)smem;               // [2][98][64] f32 = 50176 B
    float* pimg = pool + img * 6272;
    const float bv0 = bias[col];
    const float bv1 = bias[32 + col];
#pragma unroll
    for (int ts = 0; ts < 4; ts++) {
        const int tl = par + 2 * ts;
        if (tl < 7) {
#pragma unroll
            for (int g = 0; g < 2; g++) {
                const float bv = g ? bv1 : bv0;
#pragma unroll
                for (int R = 0; R < 4; R++) {
#pragma unroll
                    for (int q = 0; q < 2; q++) {
                        const int m = tl * 32 + 8 * R + 4 * hi + 2 * q;
                        if (m < 196) {
                            // C row (r&3)+8*(r>>2)+4*hi: pairs in-lane
                            const float v = fmaxf(
                                fmaxf(acc[ts][g][4 * R + 2 * q],
                                      acc[ts][g][4 * R + 2 * q + 1]) + bv, 0.f);
                            const int y = m / 14, x = m - y * 14;   // x even
                            pimg[(y * 7 + (x >> 1)) * 64 + g * 32 + col] = v;
                        }
                    }
                }
            }
        }
    }
    __syncthreads();
    // y-pool (rows 2py, 2py+1) + bf16 store, same flat layout as before
    for (int i = tid; i < 6272; i += 256) {
        const int im = i >= 3136;
        const int j = i - im * 3136;
        const int co = j & 63, s = j >> 6;
        const int py = s / 7, px = s - py * 7;
        const float* pp = pool + im * 6272;
        const float v = fmaxf(pp[((2 * py) * 7 + px) * 64 + co],
                              pp[((2 * py + 1) * 7 + px) * 64 + co]);
        flat[(size_t)(2 * bp + im) * 3136 + j] = f2bf(v);
    }
}

// ---------------------------------------------------------------------------
// Kernel C: fc1 MFMA GEMM. out[2048,1024] = relu(A[2048,3136] @ B^T + b), bf16.
// Tile 128x64, 4 waves (2x2 of 64x32), BK=32.
// ---------------------------------------------------------------------------
__global__ __launch_bounds__(256) void k_fc1_mfma(
    const unsigned short* __restrict__ A,     // [2048][3136] bf16
    const unsigned short* __restrict__ Bw,    // [1024][3136] bf16 (permuted)
    const float* __restrict__ bias,
    unsigned short* __restrict__ out)         // [2048][1024] bf16
{
    __shared__ unsigned short As[128 * 40];   // +8 pad: conflict-free b128 reads
    __shared__ unsigned short Bs[64 * 40];
    const int tid = threadIdx.x;
    const int m0 = blockIdx.y * 128;
    const int n0 = blockIdx.x * 64;
    const int wave = tid >> 6, lane = tid & 63;
    const int laneM = lane & 15, chunk = lane >> 4;
    const int wr = (wave >> 1) * 64;
    const int wc = (wave & 1) * 32;

    const int arow = tid >> 1;                // 0..127
    const int aco  = (tid & 1) * 16;          // short offset (2 chunks)
    const int brow = tid >> 2;                // 0..63
    const int bco  = (tid & 3) * 8;

    f32x4 acc[4][2];
#pragma unroll
    for (int i = 0; i < 4; i++)
#pragma unroll
        for (int j = 0; j < 2; j++) acc[i][j] = (f32x4){0.f, 0.f, 0.f, 0.f};

    const unsigned short* aptr = A  + (size_t)(m0 + arow) * 3136 + aco;
    const unsigned short* bptr = Bw + (size_t)(n0 + brow) * 3136 + bco;

    for (int k0 = 0; k0 < 3136; k0 += 32) {
        const bf16x8 a0 = *(const bf16x8*)(aptr);
        const bf16x8 a1 = *(const bf16x8*)(aptr + 8);
        const bf16x8 bb = *(const bf16x8*)(bptr);
        aptr += 32; bptr += 32;
        __syncthreads();
        *(bf16x8*)&As[arow * 40 + aco] = a0;
        *(bf16x8*)&As[arow * 40 + aco + 8] = a1;
        *(bf16x8*)&Bs[brow * 40 + bco] = bb;
        __syncthreads();

        bf16x8 af[4], bf[2];
#pragma unroll
        for (int rt = 0; rt < 4; rt++)
            af[rt] = *(const bf16x8*)&As[(wr + rt * 16 + laneM) * 40 + chunk * 8];
#pragma unroll
        for (int ct = 0; ct < 2; ct++)
            bf[ct] = *(const bf16x8*)&Bs[(wc + ct * 16 + laneM) * 40 + chunk * 8];
#pragma unroll
        for (int rt = 0; rt < 4; rt++)
#pragma unroll
            for (int ct = 0; ct < 2; ct++)
                acc[rt][ct] = __builtin_amdgcn_mfma_f32_16x16x32_bf16(
                    af[rt], bf[ct], acc[rt][ct], 0, 0, 0);
    }

#pragma unroll
    for (int ct = 0; ct < 2; ct++) {
        const int col = n0 + wc + ct * 16 + laneM;
        const float bvv = bias[col];
#pragma unroll
        for (int rt = 0; rt < 4; rt++) {
#pragma unroll
            for (int r = 0; r < 4; r++) {
                const int row = m0 + wr + rt * 16 + chunk * 4 + r;
                out[(size_t)row * 1024 + col] =
                    f2bf(fmaxf(acc[rt][ct][r] + bvv, 0.f));
            }
        }
    }
}

// ---------------------------------------------------------------------------
// Kernel D: fc2. act bf16 [2048][1024] @ w[10][1024]^T + b -> fp32 [2048][10]
// ---------------------------------------------------------------------------
__global__ __launch_bounds__(256) void k_fc2(
    const unsigned short* __restrict__ act,
    const float* __restrict__ w,
    const float* __restrict__ bias,
    float* __restrict__ out)
{
    const int row  = blockIdx.x * 4 + (threadIdx.x >> 6);
    const int lane = threadIdx.x & 63;
    const unsigned short* a = act + (size_t)row * 1024;
    float acc[10] = {};
    for (int k = lane; k < 1024; k += 64) {
        const float av = __builtin_bit_cast(float, (unsigned)a[k] << 16);
#pragma unroll
        for (int j = 0; j < 10; j++)
            acc[j] = fmaf(av, w[j * 1024 + k], acc[j]);
    }
#pragma unroll
    for (int j = 0; j < 10; j++) {
        float s = acc[j];
#pragma unroll
        for (int off = 32; off; off >>= 1) s += __shfl_xor(s, off);
        if (lane == 0) out[(size_t)row * 10 + j] = s + bias[j];
    }
}

// ---------------------------------------------------------------------------
extern "C" void kernel_launch(void* const* d_in, const int* in_sizes, int n_in,
                              void* d_out, int out_size, void* d_ws, size_t ws_size,
                              hipStream_t stream)
{
    const float* x   = (const float*)d_in[0];
    const float* w1  = (const float*)d_in[1];
    const float* tr  = (const float*)d_in[2];
    const float* w2  = (const float*)d_in[3];
    const float* b2  = (const float*)d_in[4];
    const float* fw1 = (const float*)d_in[5];
    const float* fb1 = (const float*)d_in[6];
    const float* fw2 = (const float*)d_in[7];
    const float* fb2 = (const float*)d_in[8];
    float* out = (float*)d_out;

    char* ws = (char*)d_ws;
    unsigned short* padded1 = (unsigned short*)ws;                    // 42,467,328 B
    unsigned short* flat    = (unsigned short*)(ws + 42467328);       // 12,845,056 B
    unsigned short* fc1out  = (unsigned short*)(ws + 55312384);       //  4,194,304 B
    unsigned short* wt2     = (unsigned short*)(ws + 59506688);       //    102,400 B
    unsigned short* fw1p    = (unsigned short*)(ws + 59609088);       //  6,422,528 B

    k_prep_w2<<<200, 256, 0, stream>>>(w2, wt2);
    k_prep_fw1<<<1024, 256, 0, stream>>>(fw1, fw1p);
    k_conv1_topk_pool<<<2048, 256, 0, stream>>>(x, w1, tr, padded1);
    k_conv2_mfma<<<1024, 256, 0, stream>>>(padded1, wt2, b2, flat);
    k_fc1_mfma<<<dim3(16, 16), 256, 0, stream>>>(flat, fw1p, fb1, fc1out);
    k_fc2<<<512, 256, 0, stream>>>(fc1out, fw2, fb2, out);
}